// Round 2
// baseline (32893.488 us; speedup 1.0000x reference)
//
#include <hip/hip_runtime.h>
#include <stdint.h>
#include <stddef.h>

#define Bq 128
#define Tq 512
#define Vq 32000
#define Dq 1024
#define Hq 2048

typedef __attribute__((ext_vector_type(8))) _Float16 h8;   // 8 x fp16 (4 VGPR)
typedef __attribute__((ext_vector_type(4))) float f4;

__device__ __forceinline__ float h2f(unsigned short u){
  _Float16 h; __builtin_memcpy(&h, &u, 2); return (float)h;
}
__device__ __forceinline__ unsigned short f2h(float f){
  _Float16 h = (_Float16)f; unsigned short u; __builtin_memcpy(&u, &h, 2); return u;
}
__device__ __forceinline__ float fast_tanh(float x){
  float e = __expf(2.0f * x);              // v_exp_f32 based
  return 1.0f - 2.0f / (e + 1.0f);
}

// ---------------- casts / transposes ----------------

__global__ void cast_emb(const float* __restrict__ in, unsigned short* __restrict__ out, long n4){
  long i = (long)blockIdx.x * blockDim.x + threadIdx.x;
  long stride = (long)gridDim.x * blockDim.x;
  for (; i < n4; i += stride){
    float4 v = ((const float4*)in)[i];
    ushort4 o;
    o.x = f2h(v.x); o.y = f2h(v.y); o.z = f2h(v.z); o.w = f2h(v.w);
    ((ushort4*)out)[i] = o;
  }
}

// in[K][N] f32 -> out[N][K] fp16
__global__ void transpose_cast(const float* __restrict__ in, unsigned short* __restrict__ out, int K, int N){
  __shared__ float tile[32][33];
  int n0 = blockIdx.x * 32, k0 = blockIdx.y * 32;
  int tx = threadIdx.x, ty = threadIdx.y;
  #pragma unroll
  for (int i = 0; i < 32; i += 8)
    tile[ty + i][tx] = in[(size_t)(k0 + ty + i) * N + n0 + tx];
  __syncthreads();
  #pragma unroll
  for (int i = 0; i < 32; i += 8)
    out[(size_t)(n0 + ty + i) * K + k0 + tx] = f2h(tile[tx][ty + i]);
}

// ---------------- fused GEMM accumulate (no LDS, stream from cache) ----------------
// Computes acc += A_frag x B_frag over NM mfma steps (K = NM*32), double-buffered loads.

template<int NM>
__device__ __forceinline__ void gemm_acc(f4& acc,
    const unsigned short* __restrict__ ap, const unsigned short* __restrict__ bp){
  h8 a0[8], a1[8], bb0[8], bb1[8];
  #pragma unroll
  for (int u = 0; u < 8; ++u){
    a0[u]  = *(const h8*)(const void*)(ap + u * 32);
    bb0[u] = *(const h8*)(const void*)(bp + u * 32);
  }
  #pragma unroll
  for (int g0 = 0; g0 < NM; g0 += 16){
    if (g0 + 8 < NM){
      #pragma unroll
      for (int u = 0; u < 8; ++u){
        a1[u]  = *(const h8*)(const void*)(ap + (g0 + 8 + u) * 32);
        bb1[u] = *(const h8*)(const void*)(bp + (g0 + 8 + u) * 32);
      }
    }
    #pragma unroll
    for (int u = 0; u < 8; ++u)
      acc = __builtin_amdgcn_mfma_f32_16x16x32_f16(a0[u], bb0[u], acc, 0, 0, 0);
    if (g0 + 16 < NM){
      #pragma unroll
      for (int u = 0; u < 8; ++u){
        a0[u]  = *(const h8*)(const void*)(ap + (g0 + 16 + u) * 32);
        bb0[u] = *(const h8*)(const void*)(bp + (g0 + 16 + u) * 32);
      }
    }
    if (g0 + 8 < NM){
      #pragma unroll
      for (int u = 0; u < 8; ++u)
        acc = __builtin_amdgcn_mfma_f32_16x16x32_f16(a1[u], bb1[u], acc, 0, 0, 0);
    }
  }
}

// ---------------- fused 2-layer persistent RNN ----------------
// 256 blocks x 512 threads (1 block/CU guaranteed resident: 4KB LDS, <=256 VGPR).
// Block (mt,nt): rows [mt*32,+32) x cols [nt*32,+32). 8 waves = (wm,wn,ks):
// wave = 16x16 C tile over K-half ks; K-halves reduced via tiny LDS.
// Per step: phase1 h0_t -> grid barrier -> phase2 h1_t -> grid barrier.

__global__ __launch_bounds__(512, 2) void rnn_fused(
    const unsigned short* __restrict__ embh,   // [V][1024] fp16
    const int* __restrict__ tokens,            // [B][T] int32 or int64 (sniffed)
    const unsigned short* __restrict__ Wih0T,  // [2048][1024] fp16  (T[n][k] = W[k][n])
    const unsigned short* __restrict__ Whh0T,  // [2048][2048]
    const unsigned short* __restrict__ Wih1T,  // [2048][2048]
    const unsigned short* __restrict__ Whh1T,  // [2048][2048]
    const float* __restrict__ b0,
    const float* __restrict__ b1,
    unsigned short* __restrict__ h0buf,        // [2][128][2048] fp16, zeroed
    unsigned short* __restrict__ h1buf,        // [2][128][2048] fp16, zeroed
    const int* __restrict__ lengths,
    unsigned int* __restrict__ counter)        // zeroed
{
  __shared__ float red[2][2][16][16];          // 4 KB K-split reduce
  const int tid = threadIdx.x, l = tid & 63, w = tid >> 6;
  const int wm = w & 1, wn = (w >> 1) & 1, ks = w >> 2;
  const int xcd = blockIdx.x & 7, j = blockIdx.x >> 3;
  const int nt = xcd * 8 + (j & 7), mt = j >> 3;   // XCD-clustered col slices
  const int m0 = mt * 32, n0 = nt * 32;
  const int fr = l & 15, fo = (l >> 4) * 8;

  const int arow = m0 + wm * 16 + fr;          // A-frag row (batch idx)
  const int col  = n0 + wn * 16 + fr;          // B-frag col / C col
  const int erow = m0 + wm * 16 + (l >> 4) * 4;// epilogue row base

  const bool w64 = ((tokens[1] | tokens[3] | tokens[5] | tokens[7]) == 0);
  int lenr[4];
  #pragma unroll
  for (int r = 0; r < 4; ++r) lenr[r] = lengths[erow + r];
  const float bias0 = b0[col], bias1 = b1[col];

  const unsigned short* bp_ih0 = Wih0T + (size_t)col * Dq + ks * 512 + fo;
  const unsigned short* bp_hh0 = Whh0T + (size_t)col * Hq + ks * 1024 + fo;
  const unsigned short* bp_ih1 = Wih1T + (size_t)col * Hq + ks * 1024 + fo;
  const unsigned short* bp_hh1 = Whh1T + (size_t)col * Hq + ks * 1024 + fo;
  const int  hoff_a  = arow * Hq + ks * 1024 + fo;   // A offset in compact h
  const long tokbase = (long)arow * Tq;

  for (int t = 0; t < Tq; ++t){
    const int cur = t & 1, prv = cur ^ 1;
    unsigned short*       h0c = h0buf + cur * (Bq * Hq);
    const unsigned short* h0p = h0buf + prv * (Bq * Hq);
    unsigned short*       h1c = h1buf + cur * (Bq * Hq);
    const unsigned short* h1p = h1buf + prv * (Bq * Hq);

    // ---------- phase 1: h0_t = tanh(emb[tok_t] @ Wih0 + h0_{t-1} @ Whh0) ----------
    f4 acc = {0.f, 0.f, 0.f, 0.f};
    {
      int tok = w64 ? tokens[2 * (tokbase + t)] : tokens[tokbase + t];
      gemm_acc<16>(acc, embh + (size_t)tok * Dq + ks * 512 + fo, bp_ih0);
      if (t > 0) gemm_acc<32>(acc, h0p + hoff_a, bp_hh0);
    }
    if (ks == 1){
      #pragma unroll
      for (int r = 0; r < 4; ++r) red[wm][wn][(l >> 4) * 4 + r][fr] = acc[r];
    }
    __syncthreads();
    if (ks == 0){
      #pragma unroll
      for (int r = 0; r < 4; ++r){
        float a = acc[r] + red[wm][wn][(l >> 4) * 4 + r][fr];
        int row = erow + r;
        float hprev = h2f(h0p[row * Hq + col]);
        float hn = fast_tanh(a + bias0);
        float ho = (t < lenr[r]) ? hn : hprev;
        h0c[row * Hq + col] = f2h(ho);
      }
    }
    // grid barrier (publishes h0_t)
    __syncthreads();
    if (tid == 0){
      __hip_atomic_fetch_add(counter, 1u, __ATOMIC_RELEASE, __HIP_MEMORY_SCOPE_AGENT);
      unsigned target = (unsigned)(2 * t + 1) * gridDim.x;
      while (__hip_atomic_load(counter, __ATOMIC_RELAXED, __HIP_MEMORY_SCOPE_AGENT) < target)
        __builtin_amdgcn_s_sleep(2);
      __builtin_amdgcn_fence(__ATOMIC_ACQUIRE, "agent");
    }
    __syncthreads();

    // ---------- phase 2: h1_t = tanh(h0_t @ Wih1 + h1_{t-1} @ Whh1) ----------
    acc = (f4){0.f, 0.f, 0.f, 0.f};
    gemm_acc<32>(acc, h0c + hoff_a, bp_ih1);
    if (t > 0) gemm_acc<32>(acc, h1p + hoff_a, bp_hh1);
    if (ks == 1){
      #pragma unroll
      for (int r = 0; r < 4; ++r) red[wm][wn][(l >> 4) * 4 + r][fr] = acc[r];
    }
    __syncthreads();
    if (ks == 0){
      #pragma unroll
      for (int r = 0; r < 4; ++r){
        float a = acc[r] + red[wm][wn][(l >> 4) * 4 + r][fr];
        int row = erow + r;
        float hprev = h2f(h1p[row * Hq + col]);
        float hn = fast_tanh(a + bias1);
        float ho = (t < lenr[r]) ? hn : hprev;
        h1c[row * Hq + col] = f2h(ho);
      }
    }
    if (t < Tq - 1){
      __syncthreads();
      if (tid == 0){
        __hip_atomic_fetch_add(counter, 1u, __ATOMIC_RELEASE, __HIP_MEMORY_SCOPE_AGENT);
        unsigned target = (unsigned)(2 * t + 2) * gridDim.x;
        while (__hip_atomic_load(counter, __ATOMIC_RELAXED, __HIP_MEMORY_SCOPE_AGENT) < target)
          __builtin_amdgcn_s_sleep(2);
        __builtin_amdgcn_fence(__ATOMIC_ACQUIRE, "agent");
      }
      __syncthreads();
    }
  }
}

__global__ void h2f_out(const unsigned short* __restrict__ in, float* __restrict__ out, int n){
  int i = blockIdx.x * blockDim.x + threadIdx.x;
  if (i < n) out[i] = h2f(in[i]);
}

// ---------------- launch ----------------

extern "C" void kernel_launch(void* const* d_in, const int* in_sizes, int n_in,
                              void* d_out, int out_size, void* d_ws, size_t ws_size,
                              hipStream_t stream)
{
  (void)in_sizes; (void)n_in; (void)out_size; (void)ws_size;
  const int*   tokens  = (const int*)d_in[0];
  const int*   lengths = (const int*)d_in[1];
  const float* emb     = (const float*)d_in[2];
  const float* Wih0    = (const float*)d_in[3];
  const float* Whh0    = (const float*)d_in[4];
  const float* b0      = (const float*)d_in[5];
  const float* Wih1    = (const float*)d_in[6];
  const float* Whh1    = (const float*)d_in[7];
  const float* b1      = (const float*)d_in[8];

  char* ws = (char*)d_ws;
  size_t off = 0;
  auto alloc = [&](size_t bytes)->char*{
    char* p = ws + off; off += (bytes + 255) & ~(size_t)255; return p;
  };
  unsigned short* embh  = (unsigned short*)alloc((size_t)Vq * Dq * 2);   // 65.5 MB
  unsigned short* WTih0 = (unsigned short*)alloc((size_t)Hq * Dq * 2);   //  4 MB
  unsigned short* WThh0 = (unsigned short*)alloc((size_t)Hq * Hq * 2);   //  8 MB
  unsigned short* WTih1 = (unsigned short*)alloc((size_t)Hq * Hq * 2);   //  8 MB
  unsigned short* WThh1 = (unsigned short*)alloc((size_t)Hq * Hq * 2);   //  8 MB
  unsigned short* h0buf = (unsigned short*)alloc((size_t)2 * Bq * Hq * 2);
  unsigned short* h1buf = (unsigned short*)alloc((size_t)2 * Bq * Hq * 2);
  unsigned int*   counter = (unsigned int*)alloc(256);
  // total ~97 MB

  cast_emb<<<2048, 256, 0, stream>>>(emb, embh, (long)Vq * Dq / 4);
  transpose_cast<<<dim3(Hq / 32, Dq / 32), dim3(32, 8), 0, stream>>>(Wih0, WTih0, Dq, Hq);
  transpose_cast<<<dim3(Hq / 32, Hq / 32), dim3(32, 8), 0, stream>>>(Whh0, WThh0, Hq, Hq);
  transpose_cast<<<dim3(Hq / 32, Hq / 32), dim3(32, 8), 0, stream>>>(Wih1, WTih1, Hq, Hq);
  transpose_cast<<<dim3(Hq / 32, Hq / 32), dim3(32, 8), 0, stream>>>(Whh1, WThh1, Hq, Hq);

  hipMemsetAsync(h0buf, 0, (size_t)2 * Bq * Hq * 2, stream);
  hipMemsetAsync(h1buf, 0, (size_t)2 * Bq * Hq * 2, stream);
  hipMemsetAsync(counter, 0, 256, stream);

  rnn_fused<<<256, 512, 0, stream>>>(embh, tokens, WTih0, WThh0, WTih1, WThh1,
                                     b0, b1, h0buf, h1buf, lengths, counter);

  h2f_out<<<(Bq * Hq + 255) / 256, 256, 0, stream>>>(h1buf + Bq * Hq, (float*)d_out, Bq * Hq);
}

// Round 3
// 29328.604 us; speedup vs baseline: 1.1215x; 1.1215x over previous
//
#include <hip/hip_runtime.h>
#include <stdint.h>
#include <stddef.h>

#define Bq 128
#define Tq 512
#define Vq 32000
#define Dq 1024
#define Hq 2048
#define BH (Bq * Hq)

typedef __attribute__((ext_vector_type(8))) _Float16 h8;   // 8 x fp16
typedef __attribute__((ext_vector_type(4))) float f4;

__device__ __forceinline__ float h2f(unsigned short u){
  _Float16 h; __builtin_memcpy(&h, &u, 2); return (float)h;
}
__device__ __forceinline__ unsigned short f2h(float f){
  _Float16 h = (_Float16)f; unsigned short u; __builtin_memcpy(&u, &h, 2); return u;
}
__device__ __forceinline__ float fast_tanh(float x){
  float e = __expf(2.0f * x);
  return 1.0f - 2.0f / (e + 1.0f);
}

// ---------------- preprocessing ----------------

__global__ void cast_emb(const float* __restrict__ in, unsigned short* __restrict__ out, long n4){
  long i = (long)blockIdx.x * blockDim.x + threadIdx.x;
  long stride = (long)gridDim.x * blockDim.x;
  for (; i < n4; i += stride){
    float4 v = ((const float4*)in)[i];
    ushort4 o;
    o.x = f2h(v.x); o.y = f2h(v.y); o.z = f2h(v.z); o.w = f2h(v.w);
    ((ushort4*)out)[i] = o;
  }
}

// in[K][N] f32 -> out[N][K] fp16
__global__ void transpose_cast(const float* __restrict__ in, unsigned short* __restrict__ out, int K, int N){
  __shared__ float tile[32][33];
  int n0 = blockIdx.x * 32, k0 = blockIdx.y * 32;
  int tx = threadIdx.x, ty = threadIdx.y;
  #pragma unroll
  for (int i = 0; i < 32; i += 8)
    tile[ty + i][tx] = in[(size_t)(k0 + ty + i) * N + n0 + tx];
  __syncthreads();
  #pragma unroll
  for (int i = 0; i < 32; i += 8)
    out[(size_t)(n0 + ty + i) * K + k0 + tx] = f2h(tile[tx][ty + i]);
}

__global__ void h2f_out(const unsigned short* __restrict__ in, float* __restrict__ out, int n){
  int i = blockIdx.x * blockDim.x + threadIdx.x;
  if (i < n) out[i] = h2f(in[i]);
}

// ---------------- inner GEMM: acc[MT][NT] += A(global) x B(LDS) ----------------
// A-frag (16x16x32): lane row = l&15, k = (l>>4)*8 + frag*32. B from swizzled LDS.
// 16-frag-deep A prefetch; B read once per (kf,nt), reused over MT.

template<int MT, int NT, int KF>
__device__ __forceinline__ void mm16(f4 (&acc)[MT][NT],
    const char* const (&ap)[MT], const char* Wl,
    const int (&bb)[NT], const int (&swz)[NT])
{
  h8 ab[16];
  #pragma unroll
  for (int kf = 0; kf < 4 && kf < KF; ++kf)
    #pragma unroll
    for (int mt = 0; mt < MT; ++mt)
      ab[kf * MT + mt] = *(const h8*)(ap[mt] + kf * 64);

  #pragma unroll
  for (int kf = 0; kf < KF; ++kf){
    h8 b[NT];
    #pragma unroll
    for (int nt = 0; nt < NT; ++nt)
      b[nt] = *(const h8*)(Wl + ((bb[nt] + kf * 64) ^ swz[nt]));
    #pragma unroll
    for (int mt = 0; mt < MT; ++mt)
      #pragma unroll
      for (int nt = 0; nt < NT; ++nt)
        acc[mt][nt] = __builtin_amdgcn_mfma_f32_16x16x32_f16(ab[(kf & 3) * MT + mt], b[nt], acc[mt][nt], 0, 0, 0);
    if (kf + 4 < KF){
      #pragma unroll
      for (int mt = 0; mt < MT; ++mt)
        ab[(kf & 3) * MT + mt] = *(const h8*)(ap[mt] + (kf + 4) * 64);
    }
  }
}

// ---------------- hierarchical grid barrier ----------------

__device__ __forceinline__ void gbar(unsigned* flags, unsigned* gctr, int bid, int it){
  __syncthreads();
  if (threadIdx.x == 0){
    int xcd = bid & 7, sub = bid >> 3;
    __hip_atomic_fetch_add(&flags[xcd * 32 + sub], 1u, __ATOMIC_RELEASE, __HIP_MEMORY_SCOPE_AGENT);
    if (sub == 0){
      for (int j = 0; j < 32; ++j)
        while (__hip_atomic_load(&flags[xcd * 32 + j], __ATOMIC_RELAXED, __HIP_MEMORY_SCOPE_AGENT) < (unsigned)(it + 1))
          __builtin_amdgcn_s_sleep(1);
      __hip_atomic_fetch_add(gctr, 1u, __ATOMIC_RELEASE, __HIP_MEMORY_SCOPE_AGENT);
    }
    while (__hip_atomic_load(gctr, __ATOMIC_RELAXED, __HIP_MEMORY_SCOPE_AGENT) < (unsigned)(8 * (it + 1)))
      __builtin_amdgcn_s_sleep(2);
    __builtin_amdgcn_fence(__ATOMIC_ACQUIRE, "agent");
  }
  __syncthreads();
}

// ---------------- 4-role persistent pipeline ----------------
// roles: 0=ih0 (32 blk, xcd0)  1=hh0 (64 blk, xcd1-2)  2=ih1 (64 blk, xcd3-4)
//        3=hh1 (64 blk, xcd5-6)  idle (32 blk, xcd7)
// iter i: G0: P0_i = emb_i@Wih0+b0 ; G1: h0_{i-1} = tanh(P0 + h0_{i-2}@Whh0)
//         G2: P1_{i-2} = h0_{i-2}@Wih1+b1 ; G3: h1_{i-3} = tanh(P1 + h1_{i-4}@Whh1)

__global__ __launch_bounds__(512, 2) void rnn4(
    const unsigned short* __restrict__ embh,
    const int* __restrict__ tokens,
    const unsigned short* __restrict__ Wih0T,  // [2048][1024]
    const unsigned short* __restrict__ Whh0T,  // [2048][2048]
    const unsigned short* __restrict__ Wih1T,  // [2048][2048]
    const unsigned short* __restrict__ Whh1T,  // [2048][2048]
    const float* __restrict__ b0,
    const float* __restrict__ b1,
    unsigned short* __restrict__ h0,    // [2][128][2048] zeroed
    unsigned short* __restrict__ h1,    // [2][128][2048] zeroed
    unsigned short* __restrict__ P0,    // [2][128][2048]
    unsigned short* __restrict__ P1a,   // [2][128][2048]
    unsigned short* __restrict__ P1b,   // [2][128][2048]
    const int* __restrict__ lengths,
    unsigned* __restrict__ flags,       // [8][32] zeroed
    unsigned* __restrict__ gctr)        // zeroed
{
  extern __shared__ char lds[];
  char* Wl = lds;
  char* zone = lds + 131072;

  const int bid = blockIdx.x;
  const int xcd = bid & 7, sub = bid >> 3;
  const int tid = threadIdx.x, l = tid & 63, w = tid >> 6;
  const int mw = w & 1, kw = w >> 1;          // 2 M-halves x 4 K-slices
  const int fr = l & 15, q = l >> 4;

  int role = -1, tile = 0;
  if (xcd == 0){ role = 0; tile = sub; }
  else if (xcd <= 2){ role = 1; tile = (xcd - 1) * 32 + sub; }
  else if (xcd <= 4){ role = 2; tile = (xcd - 3) * 32 + sub; }
  else if (xcd <= 6){ role = 3; tile = (xcd - 5) * 32 + sub; }

  const bool ihrole = (role == 0 || role == 2);
  const int kh = (role == 2) ? (tile & 1) : 0;
  const int c0 = (role == 0) ? tile * 64 : (role == 2) ? (tile >> 1) * 64 : tile * 32;

  // ---- fill W slice into swizzled LDS (once) ----
  if (role >= 0){
    const unsigned short* src; int NC, KC, srcK, kofs;
    if (role == 0){ src = Wih0T; NC = 64; KC = 1024; srcK = 1024; kofs = 0; }
    else if (role == 2){ src = Wih1T; NC = 64; KC = 1024; srcK = 2048; kofs = kh * 1024; }
    else { src = (role == 1) ? Whh0T : Whh1T; NC = 32; KC = 2048; srcK = 2048; kofs = 0; }
    int nch = NC * (KC / 8);
    for (int i2 = tid; i2 < nch; i2 += 512){
      int c = i2 / (KC / 8), kg = i2 % (KC / 8);
      uint4 v = *(const uint4*)(src + (size_t)(c0 + c) * srcK + kofs + kg * 8);
      int byte = (c * KC + kg * 8) * 2 ^ ((c & 31) << 4);
      *(uint4*)(Wl + byte) = v;
    }
  }
  __syncthreads();

  // ---- per-lane constants ----
  bool w64 = false;
  if (role == 0) w64 = ((tokens[1] | tokens[3] | tokens[5] | tokens[7]) == 0);

  int lenr[4][4];
  if (role == 1 || role == 3){
    #pragma unroll
    for (int mt = 0; mt < 4; ++mt)
      #pragma unroll
      for (int r = 0; r < 4; ++r)
        lenr[mt][r] = lengths[mw * 64 + mt * 16 + q * 4 + r];
  }
  float biasv[4] = {0.f, 0.f, 0.f, 0.f};
  if (role == 0){
    #pragma unroll
    for (int nt = 0; nt < 4; ++nt) biasv[nt] = b0[c0 + nt * 16 + fr];
  } else if (role == 2 && kh == 0){
    #pragma unroll
    for (int nt = 0; nt < 4; ++nt) biasv[nt] = b1[c0 + nt * 16 + fr];
  }

  for (int it = 0; it < 515; ++it){
    if (ihrole){
      // ======== ih path: MT=4 NT=4 KF=8, K-slice 256 ========
      const int t = (role == 0) ? it : it - 2;
      if (t >= 0 && t <= 511){
        const int KC = 1024;
        int bb[4], swz[4];
        #pragma unroll
        for (int nt = 0; nt < 4; ++nt){
          int cl = nt * 16 + fr;
          bb[nt] = (cl * KC + kw * 256 + q * 8) * 2;
          swz[nt] = (cl & 31) << 4;
        }
        const char* ap[4];
        if (role == 0){
          #pragma unroll
          for (int mt = 0; mt < 4; ++mt){
            int row = mw * 64 + mt * 16 + fr;
            int idx = row * Tq + t;
            int tok = w64 ? tokens[2 * idx] : tokens[idx];
            ap[mt] = (const char*)(embh + (size_t)tok * 1024 + kw * 256 + q * 8);
          }
        } else {
          const unsigned short* Asrc = h0 + (t & 1) * BH;
          #pragma unroll
          for (int mt = 0; mt < 4; ++mt){
            int row = mw * 64 + mt * 16 + fr;
            ap[mt] = (const char*)(Asrc + (size_t)row * Hq + kh * 1024 + kw * 256 + q * 8);
          }
        }
        f4 acc[4][4] = {};
        mm16<4, 4, 8>(acc, ap, Wl, bb, swz);

        unsigned short* dst = ((role == 0) ? P0 : (kh == 0 ? P1a : P1b)) + (t & 1) * BH;
        #pragma unroll
        for (int mwr = 0; mwr < 2; ++mwr){
          __syncthreads();
          if (mw == mwr && kw > 0){
            #pragma unroll
            for (int mt = 0; mt < 4; ++mt)
              #pragma unroll
              for (int nt = 0; nt < 4; ++nt){
                ushort4 u = { f2h(acc[mt][nt][0]), f2h(acc[mt][nt][1]),
                              f2h(acc[mt][nt][2]), f2h(acc[mt][nt][3]) };
                *(ushort4*)(zone + (kw - 1) * 8192 + (mt * 4 + nt) * 512 + l * 8) = u;
              }
          }
          __syncthreads();
          if (mw == mwr && kw == 0){
            #pragma unroll
            for (int mt = 0; mt < 4; ++mt)
              #pragma unroll
              for (int nt = 0; nt < 4; ++nt){
                f4 s = acc[mt][nt];
                #pragma unroll
                for (int j = 0; j < 3; ++j){
                  ushort4 u = *(ushort4*)(zone + j * 8192 + (mt * 4 + nt) * 512 + l * 8);
                  s[0] += h2f(u.x); s[1] += h2f(u.y); s[2] += h2f(u.z); s[3] += h2f(u.w);
                }
                int col = c0 + nt * 16 + fr;
                #pragma unroll
                for (int r = 0; r < 4; ++r){
                  int row = mw * 64 + mt * 16 + q * 4 + r;
                  dst[(size_t)row * Hq + col] = f2h(s[r] + biasv[nt]);
                }
              }
          }
        }
      }
    } else if (role == 1 || role == 3){
      // ======== hh path: MT=4 NT=2 KF=16, K-slice 512 ========
      const int t = (role == 1) ? it - 1 : it - 3;
      if (t >= 0 && t <= 511){
        const int KC = 2048;
        int bb[2], swz[2];
        #pragma unroll
        for (int nt = 0; nt < 2; ++nt){
          int cl = nt * 16 + fr;
          bb[nt] = (cl * KC + kw * 512 + q * 8) * 2;
          swz[nt] = (cl & 31) << 4;
        }
        unsigned short* hbuf = (role == 1) ? h0 : h1;
        const unsigned short* Asrc = hbuf + ((t - 1) & 1) * BH;   // (-1)&1 == 1: zeroed
        const char* ap[4];
        #pragma unroll
        for (int mt = 0; mt < 4; ++mt){
          int row = mw * 64 + mt * 16 + fr;
          ap[mt] = (const char*)(Asrc + (size_t)row * Hq + kw * 512 + q * 8);
        }
        f4 acc[4][2] = {};
        mm16<4, 2, 16>(acc, ap, Wl, bb, swz);

        const unsigned short* Pa = ((role == 1) ? P0 : P1a) + (t & 1) * BH;
        const unsigned short* Pb = (role == 3) ? (P1b + (t & 1) * BH) : nullptr;
        unsigned short* hdst = hbuf + (t & 1) * BH;
        const unsigned short* hprv = hbuf + ((t - 1) & 1) * BH;
        #pragma unroll
        for (int mwr = 0; mwr < 2; ++mwr){
          __syncthreads();
          if (mw == mwr && kw > 0){
            #pragma unroll
            for (int mt = 0; mt < 4; ++mt)
              #pragma unroll
              for (int nt = 0; nt < 2; ++nt){
                ushort4 u = { f2h(acc[mt][nt][0]), f2h(acc[mt][nt][1]),
                              f2h(acc[mt][nt][2]), f2h(acc[mt][nt][3]) };
                *(ushort4*)(zone + (kw - 1) * 8192 + (mt * 2 + nt) * 512 + l * 8) = u;
              }
          }
          __syncthreads();
          if (mw == mwr && kw == 0){
            #pragma unroll
            for (int mt = 0; mt < 4; ++mt)
              #pragma unroll
              for (int nt = 0; nt < 2; ++nt){
                f4 s = acc[mt][nt];
                #pragma unroll
                for (int j = 0; j < 3; ++j){
                  ushort4 u = *(ushort4*)(zone + j * 8192 + (mt * 2 + nt) * 512 + l * 8);
                  s[0] += h2f(u.x); s[1] += h2f(u.y); s[2] += h2f(u.z); s[3] += h2f(u.w);
                }
                int col = c0 + nt * 16 + fr;
                #pragma unroll
                for (int r = 0; r < 4; ++r){
                  int row = mw * 64 + mt * 16 + q * 4 + r;
                  size_t o = (size_t)row * Hq + col;
                  float v = s[r] + h2f(Pa[o]);
                  if (role == 3) v += h2f(Pb[o]);
                  float hn = fast_tanh(v);
                  float hp = h2f(hprv[o]);
                  hdst[o] = f2h((t < lenr[mt][r]) ? hn : hp);
                }
              }
          }
        }
      }
    }
    if (it < 514) gbar(flags, gctr, bid, it);
  }
}

// ---------------- launch ----------------

extern "C" void kernel_launch(void* const* d_in, const int* in_sizes, int n_in,
                              void* d_out, int out_size, void* d_ws, size_t ws_size,
                              hipStream_t stream)
{
  (void)in_sizes; (void)n_in; (void)out_size; (void)ws_size;
  const int*   tokens  = (const int*)d_in[0];
  const int*   lengths = (const int*)d_in[1];
  const float* emb     = (const float*)d_in[2];
  const float* Wih0    = (const float*)d_in[3];
  const float* Whh0    = (const float*)d_in[4];
  const float* b0      = (const float*)d_in[5];
  const float* Wih1    = (const float*)d_in[6];
  const float* Whh1    = (const float*)d_in[7];
  const float* b1      = (const float*)d_in[8];

  char* ws = (char*)d_ws;
  size_t off = 0;
  auto alloc = [&](size_t bytes)->char*{
    char* p = ws + off; off += (bytes + 255) & ~(size_t)255; return p;
  };
  unsigned short* embh  = (unsigned short*)alloc((size_t)Vq * Dq * 2);
  unsigned short* WTih0 = (unsigned short*)alloc((size_t)Hq * Dq * 2);
  unsigned short* WThh0 = (unsigned short*)alloc((size_t)Hq * Hq * 2);
  unsigned short* WTih1 = (unsigned short*)alloc((size_t)Hq * Hq * 2);
  unsigned short* WThh1 = (unsigned short*)alloc((size_t)Hq * Hq * 2);
  unsigned short* h0b   = (unsigned short*)alloc((size_t)2 * BH * 2);
  unsigned short* h1b   = (unsigned short*)alloc((size_t)2 * BH * 2);
  unsigned short* P0b   = (unsigned short*)alloc((size_t)2 * BH * 2);
  unsigned short* P1ab  = (unsigned short*)alloc((size_t)2 * BH * 2);
  unsigned short* P1bb  = (unsigned short*)alloc((size_t)2 * BH * 2);
  unsigned*       flags = (unsigned*)alloc(8 * 32 * 4);
  unsigned*       gctr  = (unsigned*)alloc(256);

  cast_emb<<<2048, 256, 0, stream>>>(emb, embh, (long)Vq * Dq / 4);
  transpose_cast<<<dim3(Hq / 32, Dq / 32), dim3(32, 8), 0, stream>>>(Wih0, WTih0, Dq, Hq);
  transpose_cast<<<dim3(Hq / 32, Hq / 32), dim3(32, 8), 0, stream>>>(Whh0, WThh0, Hq, Hq);
  transpose_cast<<<dim3(Hq / 32, Hq / 32), dim3(32, 8), 0, stream>>>(Wih1, WTih1, Hq, Hq);
  transpose_cast<<<dim3(Hq / 32, Hq / 32), dim3(32, 8), 0, stream>>>(Whh1, WThh1, Hq, Hq);

  hipMemsetAsync(h0b, 0, (size_t)2 * BH * 2, stream);
  hipMemsetAsync(h1b, 0, (size_t)2 * BH * 2, stream);
  hipMemsetAsync(flags, 0, 8 * 32 * 4, stream);
  hipMemsetAsync(gctr, 0, 256, stream);

  hipFuncSetAttribute((const void*)rnn4, hipFuncAttributeMaxDynamicSharedMemorySize, 155648);
  rnn4<<<256, 512, 155648, stream>>>(embh, tokens, WTih0, WThh0, WTih1, WThh1,
                                     b0, b1, h0b, h1b, P0b, P1ab, P1bb,
                                     lengths, flags, gctr);

  h2f_out<<<(BH + 255) / 256, 256, 0, stream>>>(h1b + BH, (float*)d_out, BH);
}